// Round 3
// baseline (674.274 us; speedup 1.0000x reference)
//
#include <hip/hip_runtime.h>
#include <hip/hip_bf16.h>

// Problem constants
#define S_TOK    8192
#define D_DIM    2048
#define N_EXP    64
#define CAPACITY 128
#define SEC      ((size_t)S_TOK * N_EXP * CAPACITY)  // 67108864

// GEMM tiling: 64 tokens x 64 experts per block, BK=64, split-K=4
#define KS2   4
#define KR2   (D_DIM / KS2)   // 512
#define BT    64
#define BK    64
#define LSTR  68              // padded LDS stride (mult of 4 for b128 alignment)

// ---------------------------------------------------------------------------
// K1a: LDS-tiled fp32 GEMM, software-pipelined (register prefetch of tile
// kt+1 issued before compute of tile kt). part[split][token][e].
// 512 blocks x 256 threads, 2 blocks/CU. Each thread: 4x4 register tile.
// ---------------------------------------------------------------------------
__global__ __launch_bounds__(256, 2) void k1a_gemm(const float* __restrict__ x,
                                                   const float* __restrict__ wg,
                                                   float* __restrict__ part) {
    __shared__ __align__(16) float Xs[BT * LSTR];  // Xs[t][k]
    __shared__ __align__(16) float Ws[BK * LSTR];  // Ws[k][e] (transposed)

    const int tid   = threadIdx.x;
    const int blk   = blockIdx.x;
    const int split = blk & (KS2 - 1);
    const int tB    = (blk >> 2) * BT;

    // compute-thread mapping: 16x16 grid of threads, 4x4 outputs each
    const int tx = tid & 15, ty = tid >> 4;
    const int e0 = tx * 4,   t0 = ty * 4;

    // load-thread mapping: 16 float4 columns x 16 row-groups
    const int lcol = tid & 15;   // k chunk: floats [4*lcol, 4*lcol+3]
    const int lrow = tid >> 4;   // rows lrow, lrow+16, lrow+32, lrow+48

    float acc[4][4] = {};

    const float* xbase = x  + (size_t)tB * D_DIM + split * KR2 + 4 * lcol;
    const float* wbase = wg + split * KR2 + 4 * lcol;

    float4 gx[4], gw[4];
    // prefetch tile kt=0
#pragma unroll
    for (int j = 0; j < 4; ++j) {
        gx[j] = *(const float4*)(xbase + (size_t)(lrow + 16 * j) * D_DIM);
        gw[j] = *(const float4*)(wbase + (size_t)(lrow + 16 * j) * D_DIM);
    }

#pragma unroll 1
    for (int kt = 0; kt < KR2; kt += BK) {
        // stage prefetched registers into LDS
#pragma unroll
        for (int j = 0; j < 4; ++j) {
            *(float4*)&Xs[(lrow + 16 * j) * LSTR + 4 * lcol] = gx[j];
            const int e = lrow + 16 * j;          // transpose W: Ws[k][e]
            Ws[(4 * lcol + 0) * LSTR + e] = gw[j].x;
            Ws[(4 * lcol + 1) * LSTR + e] = gw[j].y;
            Ws[(4 * lcol + 2) * LSTR + e] = gw[j].z;
            Ws[(4 * lcol + 3) * LSTR + e] = gw[j].w;
        }
        __syncthreads();   // tile visible

        // issue next tile's global loads BEFORE compute (latency hidden)
        if (kt + BK < KR2) {
#pragma unroll
            for (int j = 0; j < 4; ++j) {
                gx[j] = *(const float4*)(xbase + (size_t)(lrow + 16 * j) * D_DIM + kt + BK);
                gw[j] = *(const float4*)(wbase + (size_t)(lrow + 16 * j) * D_DIM + kt + BK);
            }
        }

#pragma unroll
        for (int kk = 0; kk < BK; kk += 4) {
            float av[4][4];   // [tt][ki]
            float bv[4][4];   // [ki][ee]
#pragma unroll
            for (int tt = 0; tt < 4; ++tt)
                *(float4*)av[tt] = *(const float4*)&Xs[(t0 + tt) * LSTR + kk];
#pragma unroll
            for (int ki = 0; ki < 4; ++ki)
                *(float4*)bv[ki] = *(const float4*)&Ws[(kk + ki) * LSTR + e0];
#pragma unroll
            for (int tt = 0; tt < 4; ++tt)
#pragma unroll
                for (int ee = 0; ee < 4; ++ee) {
                    float a = acc[tt][ee];
                    a = fmaf(av[tt][0], bv[0][ee], a);
                    a = fmaf(av[tt][1], bv[1][ee], a);
                    a = fmaf(av[tt][2], bv[2][ee], a);
                    a = fmaf(av[tt][3], bv[3][ee], a);
                    acc[tt][ee] = a;
                }
        }
        __syncthreads();   // compute done, LDS reusable
    }

#pragma unroll
    for (int tt = 0; tt < 4; ++tt) {
        float* prow = part + ((size_t)split * S_TOK + tB + t0 + tt) * N_EXP + e0;
        *(float4*)prow = make_float4(acc[tt][0], acc[tt][1], acc[tt][2], acc[tt][3]);
    }
}

// ---------------------------------------------------------------------------
// K1b: reduce KS2 partials -> logits[64]; softmax; argmax (first max, like
// np.argmax); gate = 1/sum(exp(l-max)); per-wave me partial sums via butterfly.
// grid = 128 blocks of 64 threads; lane = token within block.
// ---------------------------------------------------------------------------
__global__ __launch_bounds__(64) void k1b_softmax(const float* __restrict__ part,
                                                  int*   __restrict__ idxArr,
                                                  float* __restrict__ gateArr,
                                                  float* __restrict__ mep) {
    const int lane  = threadIdx.x;
    const int token = blockIdx.x * 64 + lane;

    float l[N_EXP];
    {
        const float* p0 = part + (size_t)token * N_EXP;
#pragma unroll
        for (int i = 0; i < 16; ++i) ((float4*)l)[i] = ((const float4*)p0)[i];
    }
#pragma unroll 1
    for (int sp = 1; sp < KS2; ++sp) {
        const float* ps = part + ((size_t)sp * S_TOK + token) * N_EXP;
#pragma unroll
        for (int i = 0; i < 16; ++i) {
            float4 v = ((const float4*)ps)[i];
            float4* a = ((float4*)l) + i;
            a->x += v.x; a->y += v.y; a->z += v.z; a->w += v.w;
        }
    }

    // argmax (first occurrence) + max
    float best = l[0];
    int   bi   = 0;
#pragma unroll
    for (int e = 1; e < N_EXP; ++e) {
        if (l[e] > best) { best = l[e]; bi = e; }
    }

    // softmax denominator
    float sum = 0.0f;
#pragma unroll
    for (int e = 0; e < N_EXP; ++e) sum += __expf(l[e] - best);
    const float inv = 1.0f / sum;

    idxArr[token]  = bi;
    gateArr[token] = inv;   // softmax value at argmax = exp(0)/sum

    // me partials: sum over the 64 tokens (lanes) of softmax prob per expert
#pragma unroll 1
    for (int e = 0; e < N_EXP; ++e) {
        float v = __expf(l[e] - best) * inv;
#pragma unroll
        for (int off = 32; off > 0; off >>= 1) v += __shfl_xor(v, off, 64);
        if (lane == 0) mep[(size_t)blockIdx.x * N_EXP + e] = v;
    }
}

// ---------------------------------------------------------------------------
// K2: single block, 1024 threads (16 waves). Per-expert prefix count over
// tokens (ballot-based 64-token groups -> per-wave hist -> cross-wave scan ->
// within-chunk rank). Scatters combine/mask nonzeros directly (fused k4).
// Also l_aux -> out[0].
// ---------------------------------------------------------------------------
__global__ __launch_bounds__(1024) void k2_scan(const int*   __restrict__ idxArr,
                                                const float* __restrict__ mep,
                                                const float* __restrict__ gateArr,
                                                float* __restrict__ out) {
    __shared__ int   hist[16][N_EXP];
    __shared__ int   cbase[16][N_EXP];
    __shared__ int   totalSm[N_EXP];
    __shared__ float mered[8][N_EXP];

    const int tid  = threadIdx.x;
    const int lane = tid & 63;
    const int w    = tid >> 6;

    int eTok[8];

    // Phase A: per-wave-chunk histogram (lane acts as expert `lane`)
    int cnt = 0;
#pragma unroll 1
    for (int g = 0; g < 8; ++g) {
        const int s = w * 512 + g * 64 + lane;
        const int e = idxArr[s];
        eTok[g] = e;
        unsigned long long bal[6];
#pragma unroll
        for (int b = 0; b < 6; ++b) bal[b] = __ballot((e >> b) & 1);
        unsigned long long mE = ~0ull;
#pragma unroll
        for (int b = 0; b < 6; ++b) mE &= ((lane >> b) & 1) ? bal[b] : ~bal[b];
        cnt += __popcll(mE);
    }
    hist[w][lane] = cnt;
    __syncthreads();

    // Phase A2: exclusive scan across the 16 wave-chunks, per expert
    if (tid < 64) {
        int run = 0;
#pragma unroll 1
        for (int w2 = 0; w2 < 16; ++w2) {
            cbase[w2][tid] = run;
            run += hist[w2][tid];
        }
        totalSm[tid] = run;   // pre-drop count per expert (ce numerator)
    }
    // mep reduction in parallel: 512 threads
    if (tid >= 64 && tid < 576) {
        const int t2 = tid - 64;
        const int e  = t2 & 63;
        const int h  = t2 >> 6;           // 8 slices of 16 blocks
        float sacc = 0.0f;
#pragma unroll 1
        for (int p = h * 16; p < h * 16 + 16; ++p) sacc += mep[(size_t)p * N_EXP + e];
        mered[h][e] = sacc;
    }
    __syncthreads();

    // Phase B: final positions + fused scatter into combine/mask
    int runB = 0;   // lane-as-expert running count within this wave chunk
#pragma unroll 1
    for (int g = 0; g < 8; ++g) {
        const int e = eTok[g];
        unsigned long long bal[6];
#pragma unroll
        for (int b = 0; b < 6; ++b) bal[b] = __ballot((e >> b) & 1);
        unsigned long long mE = ~0ull, mT = ~0ull;
#pragma unroll
        for (int b = 0; b < 6; ++b) {
            const unsigned long long bb = bal[b];
            mE &= ((lane >> b) & 1) ? bb : ~bb;
            mT &= ((e    >> b) & 1) ? bb : ~bb;
        }
        const unsigned long long below = (1ull << lane) - 1ull;
        const int rank = __popcll(mT & below);
        const int base = cbase[w][e];
        const int runE = __shfl(runB, e, 64);
        const int pos  = base + runE + rank;
        const int s    = w * 512 + g * 64 + lane;
        if (pos < CAPACITY) {
            const size_t off = 1 + (size_t)s * (N_EXP * CAPACITY)
                             + (size_t)e * CAPACITY + pos;
            out[off]       = gateArr[s];
            out[off + SEC] = 1.0f;
        }
        runB += __popcll(mE);
    }

    // Phase C: l_aux
    if (tid < 64) {
        float me = 0.0f;
#pragma unroll
        for (int h = 0; h < 8; ++h) me += mered[h][tid];
        me *= (1.0f / (float)S_TOK);
        const float ce = (float)totalSm[tid] * (1.0f / (float)S_TOK);
        float v = me * ce;
#pragma unroll
        for (int off = 32; off > 0; off >>= 1) v += __shfl_xor(v, off, 64);
        if (tid == 0) out[0] = v * 64.0f;   // mean(me*ce)*E*E = (sum/64)*4096
    }
}

// ---------------------------------------------------------------------------
extern "C" void kernel_launch(void* const* d_in, const int* in_sizes, int n_in,
                              void* d_out, int out_size, void* d_ws, size_t ws_size,
                              hipStream_t stream) {
    const float* x  = (const float*)d_in[0];   // [8192, 2048] fp32
    const float* wg = (const float*)d_in[1];   // [64, 2048] fp32
    float* out = (float*)d_out;

    // workspace layout (bytes)
    char* ws = (char*)d_ws;
    const size_t partBytes = (size_t)KS2 * S_TOK * N_EXP * 4;   // 8 MB
    float* part    = (float*)ws;
    int*   idxArr  = (int*)  (ws + partBytes);
    float* gateArr = (float*)(ws + partBytes + S_TOK * 4);
    float* mep     = (float*)(ws + partBytes + S_TOK * 8);

    // Zero combine + mask region (out[1..]); out[0] (l_aux) written by k2.
    hipMemsetAsync((char*)d_out + 4, 0, ((size_t)out_size - 1) * sizeof(float), stream);

    k1a_gemm   <<<(S_TOK / BT) * KS2, 256,  0, stream>>>(x, wg, part);
    k1b_softmax<<<S_TOK / 64,         64,   0, stream>>>(part, idxArr, gateArr, mep);
    k2_scan    <<<1,                  1024, 0, stream>>>(idxArr, mep, gateArr, out);
}

// Round 4
// 665.648 us; speedup vs baseline: 1.0130x; 1.0130x over previous
//
#include <hip/hip_runtime.h>
#include <hip/hip_bf16.h>

// Problem constants
#define S_TOK    8192
#define D_DIM    2048
#define N_EXP    64
#define CAPACITY 128
#define SEC      ((size_t)S_TOK * N_EXP * CAPACITY)  // 67108864

// GEMM tiling: 64 tokens x 64 experts per block, BK=64, split-K=4
#define KS2   4
#define KR2   (D_DIM / KS2)   // 512
#define BT    64
#define BK    64
#define LSTR  68              // padded LDS stride (mult of 4 for b128 alignment)

#define NGEMM  (S_TOK / BT * KS2)   // 512 gemm blocks
#define NFILL  1024                 // fill blocks (2 per gemm block)
// out zero region: [0, 2*SEC] floats = 134217729. Aligned float4 region
// covers 134217728 floats = NFILL * 32768 float4; tail element handled by
// fill block 0. out[0] is overwritten with l_aux by k2 afterwards.
#define F4_PER_BLK 32768

// ---------------------------------------------------------------------------
// K1: fused zero-fill + LDS-tiled fp32 GEMM (block-role split).
//   role gemm (b%3==0): part[split][token][e] = sum_k x[t][k]*wg[e][k]
//   role fill:          zero a contiguous 512KB chunk of out
// Fill is write-BW-bound, GEMM is VALU/LDS-bound -> co-resident blocks
// overlap the two resources instead of serializing memset + gemm.
// ---------------------------------------------------------------------------
__global__ __launch_bounds__(256, 2) void k1_fill_gemm(const float* __restrict__ x,
                                                       const float* __restrict__ wg,
                                                       float* __restrict__ part,
                                                       float* __restrict__ out) {
    __shared__ __align__(16) float Xs[BT * LSTR];  // Xs[t][k]
    __shared__ __align__(16) float Ws[BK * LSTR];  // Ws[k][e] (transposed)

    const int tid = threadIdx.x;
    const int b   = blockIdx.x;

    if (b % 3 != 0) {
        // ---- fill role ----
        const int fid = (b / 3) * 2 + (b % 3) - 1;   // 0..NFILL-1
        float4* o4 = (float4*)out;
        const size_t base = (size_t)fid * F4_PER_BLK + tid;
        const float4 z = make_float4(0.f, 0.f, 0.f, 0.f);
#pragma unroll 8
        for (int i = 0; i < F4_PER_BLK / 256; ++i)
            o4[base + (size_t)i * 256] = z;
        if (fid == 0 && tid == 0) out[2 * SEC] = 0.0f;   // tail element
        return;
    }

    // ---- gemm role ----
    const int blk   = b / 3;                 // 0..511
    const int split = blk & (KS2 - 1);
    const int tB    = (blk >> 2) * BT;

    // compute-thread mapping: 16x16 grid of threads, 4x4 outputs each
    const int tx = tid & 15, ty = tid >> 4;
    const int e0 = tx * 4,   t0 = ty * 4;

    // load-thread mapping: 16 float4 columns x 16 row-groups
    const int lcol = tid & 15;
    const int lrow = tid >> 4;

    float acc[4][4] = {};

    const float* xbase = x  + (size_t)tB * D_DIM + split * KR2 + 4 * lcol;
    const float* wbase = wg + split * KR2 + 4 * lcol;

#pragma unroll 1
    for (int kt = 0; kt < KR2; kt += BK) {
        float4 gx[4], gw[4];
#pragma unroll
        for (int j = 0; j < 4; ++j) {
            gx[j] = *(const float4*)(xbase + (size_t)(lrow + 16 * j) * D_DIM + kt);
            gw[j] = *(const float4*)(wbase + (size_t)(lrow + 16 * j) * D_DIM + kt);
        }
        __syncthreads();   // previous tile's compute done
#pragma unroll
        for (int j = 0; j < 4; ++j) {
            *(float4*)&Xs[(lrow + 16 * j) * LSTR + 4 * lcol] = gx[j];
            const int e = lrow + 16 * j;          // transpose W: Ws[k][e]
            Ws[(4 * lcol + 0) * LSTR + e] = gw[j].x;
            Ws[(4 * lcol + 1) * LSTR + e] = gw[j].y;
            Ws[(4 * lcol + 2) * LSTR + e] = gw[j].z;
            Ws[(4 * lcol + 3) * LSTR + e] = gw[j].w;
        }
        __syncthreads();   // tile visible

#pragma unroll
        for (int kk = 0; kk < BK; kk += 4) {
            float av[4][4];   // [tt][ki]
            float bv[4][4];   // [ki][ee]
#pragma unroll
            for (int tt = 0; tt < 4; ++tt)
                *(float4*)av[tt] = *(const float4*)&Xs[(t0 + tt) * LSTR + kk];
#pragma unroll
            for (int ki = 0; ki < 4; ++ki)
                *(float4*)bv[ki] = *(const float4*)&Ws[(kk + ki) * LSTR + e0];
#pragma unroll
            for (int tt = 0; tt < 4; ++tt)
#pragma unroll
                for (int ee = 0; ee < 4; ++ee) {
                    float a = acc[tt][ee];
                    a = fmaf(av[tt][0], bv[0][ee], a);
                    a = fmaf(av[tt][1], bv[1][ee], a);
                    a = fmaf(av[tt][2], bv[2][ee], a);
                    a = fmaf(av[tt][3], bv[3][ee], a);
                    acc[tt][ee] = a;
                }
        }
    }

#pragma unroll
    for (int tt = 0; tt < 4; ++tt) {
        float* prow = part + ((size_t)split * S_TOK + tB + t0 + tt) * N_EXP + e0;
        *(float4*)prow = make_float4(acc[tt][0], acc[tt][1], acc[tt][2], acc[tt][3]);
    }
}

// ---------------------------------------------------------------------------
// K1b: reduce KS2 partials -> logits[64]; softmax; argmax (first max, like
// np.argmax); gate = 1/sum(exp(l-max)); per-wave me partial sums via butterfly.
// grid = 128 blocks of 64 threads; lane = token within block.
// ---------------------------------------------------------------------------
__global__ __launch_bounds__(64) void k1b_softmax(const float* __restrict__ part,
                                                  int*   __restrict__ idxArr,
                                                  float* __restrict__ gateArr,
                                                  float* __restrict__ mep) {
    const int lane  = threadIdx.x;
    const int token = blockIdx.x * 64 + lane;

    float l[N_EXP];
    {
        const float* p0 = part + (size_t)token * N_EXP;
#pragma unroll
        for (int i = 0; i < 16; ++i) ((float4*)l)[i] = ((const float4*)p0)[i];
    }
#pragma unroll 1
    for (int sp = 1; sp < KS2; ++sp) {
        const float* ps = part + ((size_t)sp * S_TOK + token) * N_EXP;
#pragma unroll
        for (int i = 0; i < 16; ++i) {
            float4 v = ((const float4*)ps)[i];
            float4* a = ((float4*)l) + i;
            a->x += v.x; a->y += v.y; a->z += v.z; a->w += v.w;
        }
    }

    // argmax (first occurrence) + max
    float best = l[0];
    int   bi   = 0;
#pragma unroll
    for (int e = 1; e < N_EXP; ++e) {
        if (l[e] > best) { best = l[e]; bi = e; }
    }

    // softmax denominator
    float sum = 0.0f;
#pragma unroll
    for (int e = 0; e < N_EXP; ++e) sum += __expf(l[e] - best);
    const float inv = 1.0f / sum;

    idxArr[token]  = bi;
    gateArr[token] = inv;   // softmax value at argmax = exp(0)/sum

    // me partials: sum over the 64 tokens (lanes) of softmax prob per expert
#pragma unroll 1
    for (int e = 0; e < N_EXP; ++e) {
        float v = __expf(l[e] - best) * inv;
#pragma unroll
        for (int off = 32; off > 0; off >>= 1) v += __shfl_xor(v, off, 64);
        if (lane == 0) mep[(size_t)blockIdx.x * N_EXP + e] = v;
    }
}

// ---------------------------------------------------------------------------
// K2: single block, 1024 threads (16 waves). Per-expert prefix count over
// tokens (ballot-based 64-token groups -> per-wave hist -> cross-wave scan ->
// within-chunk rank). Scatters combine/mask nonzeros directly (fused k4).
// Also l_aux -> out[0].
// ---------------------------------------------------------------------------
__global__ __launch_bounds__(1024) void k2_scan(const int*   __restrict__ idxArr,
                                                const float* __restrict__ mep,
                                                const float* __restrict__ gateArr,
                                                float* __restrict__ out) {
    __shared__ int   hist[16][N_EXP];
    __shared__ int   cbase[16][N_EXP];
    __shared__ int   totalSm[N_EXP];
    __shared__ float mered[8][N_EXP];

    const int tid  = threadIdx.x;
    const int lane = tid & 63;
    const int w    = tid >> 6;

    int eTok[8];

    // Phase A: per-wave-chunk histogram (lane acts as expert `lane`)
    int cnt = 0;
#pragma unroll 1
    for (int g = 0; g < 8; ++g) {
        const int s = w * 512 + g * 64 + lane;
        const int e = idxArr[s];
        eTok[g] = e;
        unsigned long long bal[6];
#pragma unroll
        for (int b = 0; b < 6; ++b) bal[b] = __ballot((e >> b) & 1);
        unsigned long long mE = ~0ull;
#pragma unroll
        for (int b = 0; b < 6; ++b) mE &= ((lane >> b) & 1) ? bal[b] : ~bal[b];
        cnt += __popcll(mE);
    }
    hist[w][lane] = cnt;
    __syncthreads();

    // Phase A2: exclusive scan across the 16 wave-chunks, per expert
    if (tid < 64) {
        int run = 0;
#pragma unroll 1
        for (int w2 = 0; w2 < 16; ++w2) {
            cbase[w2][tid] = run;
            run += hist[w2][tid];
        }
        totalSm[tid] = run;   // pre-drop count per expert (ce numerator)
    }
    // mep reduction in parallel: 512 threads
    if (tid >= 64 && tid < 576) {
        const int t2 = tid - 64;
        const int e  = t2 & 63;
        const int h  = t2 >> 6;           // 8 slices of 16 blocks
        float sacc = 0.0f;
#pragma unroll 1
        for (int p = h * 16; p < h * 16 + 16; ++p) sacc += mep[(size_t)p * N_EXP + e];
        mered[h][e] = sacc;
    }
    __syncthreads();

    // Phase B: final positions + fused scatter into combine/mask
    int runB = 0;   // lane-as-expert running count within this wave chunk
#pragma unroll 1
    for (int g = 0; g < 8; ++g) {
        const int e = eTok[g];
        unsigned long long bal[6];
#pragma unroll
        for (int b = 0; b < 6; ++b) bal[b] = __ballot((e >> b) & 1);
        unsigned long long mE = ~0ull, mT = ~0ull;
#pragma unroll
        for (int b = 0; b < 6; ++b) {
            const unsigned long long bb = bal[b];
            mE &= ((lane >> b) & 1) ? bb : ~bb;
            mT &= ((e    >> b) & 1) ? bb : ~bb;
        }
        const unsigned long long below = (1ull << lane) - 1ull;
        const int rank = __popcll(mT & below);
        const int base = cbase[w][e];
        const int runE = __shfl(runB, e, 64);
        const int pos  = base + runE + rank;
        const int s    = w * 512 + g * 64 + lane;
        if (pos < CAPACITY) {
            const size_t off = 1 + (size_t)s * (N_EXP * CAPACITY)
                             + (size_t)e * CAPACITY + pos;
            out[off]       = gateArr[s];
            out[off + SEC] = 1.0f;
        }
        runB += __popcll(mE);
    }

    // Phase C: l_aux
    if (tid < 64) {
        float me = 0.0f;
#pragma unroll
        for (int h = 0; h < 8; ++h) me += mered[h][tid];
        me *= (1.0f / (float)S_TOK);
        const float ce = (float)totalSm[tid] * (1.0f / (float)S_TOK);
        float v = me * ce;
#pragma unroll
        for (int off = 32; off > 0; off >>= 1) v += __shfl_xor(v, off, 64);
        if (tid == 0) out[0] = v * 64.0f;   // mean(me*ce)*E*E = (sum/64)*4096
    }
}

// ---------------------------------------------------------------------------
extern "C" void kernel_launch(void* const* d_in, const int* in_sizes, int n_in,
                              void* d_out, int out_size, void* d_ws, size_t ws_size,
                              hipStream_t stream) {
    const float* x  = (const float*)d_in[0];   // [8192, 2048] fp32
    const float* wg = (const float*)d_in[1];   // [64, 2048] fp32
    float* out = (float*)d_out;

    // workspace layout (bytes)
    char* ws = (char*)d_ws;
    const size_t partBytes = (size_t)KS2 * S_TOK * N_EXP * 4;   // 8 MB
    float* part    = (float*)ws;
    int*   idxArr  = (int*)  (ws + partBytes);
    float* gateArr = (float*)(ws + partBytes + S_TOK * 4);
    float* mep     = (float*)(ws + partBytes + S_TOK * 8);

    k1_fill_gemm<<<NGEMM + NFILL, 256,  0, stream>>>(x, wg, part, out);
    k1b_softmax <<<S_TOK / 64,    64,   0, stream>>>(part, idxArr, gateArr, mep);
    k2_scan     <<<1,             1024, 0, stream>>>(idxArr, mep, gateArr, out);
}